// Round 4
// baseline (90.166 us; speedup 1.0000x reference)
//
#include <hip/hip_runtime.h>

// Shapes fixed by setup_inputs(): B=32, L_enc=512, E=256, L_dec=2048.
#define B_    32
#define LENC  512
#define LDEC  2048
#define E4    64            // 256 floats = 64 float4 = one wave's lanes
#define TPB   256
#define NWAVE (TPB / 64)    // 4 waves per block
#define ROWS_PER_BLOCK 16
#define ROWS_PER_WAVE  (ROWS_PER_BLOCK / NWAVE)  // 4 consecutive d per wave
#define CHUNKS_PER_BLOCK 2
#define NBLK  ((LDEC / (ROWS_PER_BLOCK * CHUNKS_PER_BLOCK)) * B_)  // 2048

typedef float __attribute__((ext_vector_type(4))) f32x4;

// ---------------------------------------------------------------------------
// R9: attack the write-path efficiency (kernel streams ~2.7 TB/s vs 6.3
// achievable; locality/search tweaks in R8 were null, so the gap is the
// memory path, not addressing).
//  1. NON-TEMPORAL stores for out (64 MiB write-once): bypass L2, stop
//     thrashing the enc slabs (2 MiB/XCD stays resident). R4's NT regression
//     was confounded with an 8-deep register batch (VGPR 108); 4-deep NT
//     keeps VGPR ~50.
//  2. 2 chunks/block -> 2048 blocks = exactly 8 blocks/CU = 32 waves/CU:
//     whole grid resident in one round, scan amortized 2x, 32 KiB contiguous
//     stores per block.
//  Kept from R8: 1D grid b = g & 31 (XCD = b%8, enc slab L2-resident),
//  wave-ballot lower_bound (2 LDS reads + 2 ballots).
// ---------------------------------------------------------------------------
__global__ __launch_bounds__(TPB) void length_regulator_fused(
    const float4* __restrict__ enc, const int2* __restrict__ dur2,
    float4* __restrict__ out) {
  const int g     = blockIdx.x;
  const int b     = g & 31;       // XCD-aligned batch mapping
  const int cpair = g >> 5;       // 0..63
  const int t     = threadIdx.x;  // 0..255
  const int lane  = t & 63;
  const int wid   = t >> 6;       // 0..3

  __shared__ int cs[LENC];        // inclusive cumsum of durations
  __shared__ int wsum[NWAVE];

  // pair-sum scan: thread t owns durations 2t, 2t+1
  const int2 v = dur2[b * (LENC / 2) + t];
  int x = v.x + v.y;
#pragma unroll
  for (int off = 1; off < 64; off <<= 1) {
    const int y = __shfl_up(x, off, 64);
    if (lane >= off) x += y;
  }
  if (lane == 63) wsum[wid] = x;
  __syncthreads();
  int wo = 0;
#pragma unroll
  for (int w = 0; w < NWAVE; ++w) wo += (w < wid) ? wsum[w] : 0;
  const int ip = x + wo;          // inclusive through element 2t+1
  cs[2 * t + 1] = ip;
  cs[2 * t]     = ip - v.y;
  __syncthreads();

  const int total = cs[LENC - 1];
  const int bmax  = cs[8 * lane + 7];   // bucket max, reused for both chunks

  const size_t enc_base = (size_t)b * LENC * E4 + lane;

#pragma unroll
  for (int c = 0; c < CHUNKS_PER_BLOCK; ++c) {
    const int chunk = cpair * CHUNKS_PER_BLOCK + c;
    const int d0 = chunk * ROWS_PER_BLOCK + wid * ROWS_PER_WAVE;

    // wave-ballot lower bound: lo = #{j : cs[j] <= d0}
    int lo;
    {
      const unsigned long long m = __ballot(bmax <= d0);
      const int k = __popcll(m);                  // crossing bucket
      if (k >= 64) {
        lo = LENC;                                // d0 >= total
      } else {
        const unsigned long long m2 = __ballot(cs[8 * k + (lane & 7)] <= d0);
        lo = 8 * k + (int)(__popcll(m2) >> 3);    // 8 lanes per entry
      }
    }

    // sequential advance for the wave's remaining 3 rows (mean dur 3.5)
    int los[ROWS_PER_WAVE];
    los[0] = lo;
#pragma unroll
    for (int r = 1; r < ROWS_PER_WAVE; ++r) {
      while (lo < LENC && cs[lo] <= d0 + r) ++lo;
      los[r] = lo;
    }

    const size_t out_base = (size_t)b * LDEC * E4 + (size_t)d0 * E4 + lane;

    // 4 independent loads (MLP), then 4 NT stores (bypass L2)
    float4 vals[ROWS_PER_WAVE];
#pragma unroll
    for (int r = 0; r < ROWS_PER_WAVE; ++r) {
      vals[r] = make_float4(0.f, 0.f, 0.f, 0.f);
      if (d0 + r < total)
        vals[r] = enc[enc_base + (size_t)los[r] * E4];
    }
#pragma unroll
    for (int r = 0; r < ROWS_PER_WAVE; ++r)
      __builtin_nontemporal_store(
          *reinterpret_cast<const f32x4*>(&vals[r]),
          reinterpret_cast<f32x4*>(&out[out_base + (size_t)r * E4]));
  }
}

extern "C" void kernel_launch(void* const* d_in, const int* in_sizes, int n_in,
                              void* d_out, int out_size, void* d_ws, size_t ws_size,
                              hipStream_t stream) {
  const float* enc = (const float*)d_in[0];   // (B, LENC, E) fp32
  const int*   dur = (const int*)d_in[1];     // (B, LENC) int32
  // d_in[2] = decoder_max_seq_len scalar (2048), fixed by harness shapes.

  length_regulator_fused<<<dim3(NBLK), TPB, 0, stream>>>(
      (const float4*)enc, (const int2*)dur, (float4*)d_out);
}

// Round 5
// 87.917 us; speedup vs baseline: 1.0256x; 1.0256x over previous
//
#include <hip/hip_runtime.h>

// Shapes fixed by setup_inputs(): B=32, L_enc=512, E=256, L_dec=2048.
#define B_    32
#define LENC  512
#define LDEC  2048
#define E4    64            // 256 floats = 64 float4 = one wave's lanes
#define TPB   256
#define NWAVE (TPB / 64)    // 4 waves per block
#define ROWS_PER_BLOCK 16
#define ROWS_PER_WAVE  (ROWS_PER_BLOCK / NWAVE)  // 4 consecutive d per wave

// ---------------------------------------------------------------------------
// R10: revert to the R5 kernel verbatim — the session's best (87.4 µs).
// A/B ledger: R7 two-phase +5.8 (serialized prelude), R8 XCD-map+ballot +1.4,
// R9 NT-stores+2chunks +2.8. Four independent levers (L2 locality, search
// latency, store path, occupancy) all null-to-negative => the kernel is at
// its streaming floor (~64 MiB store + ~16 MiB enc read ≈ 13 µs) inside a
// window dominated by harness fills (256 MiB poison @43.5 µs + 64 MiB memset
// @10.7 µs + reset() dispatch gaps ≈ 70 µs fixed).
// ---------------------------------------------------------------------------
__global__ __launch_bounds__(TPB) void length_regulator_fused(
    const float4* __restrict__ enc, const int2* __restrict__ dur2,
    float4* __restrict__ out) {
  const int t    = threadIdx.x;   // 0..255
  const int lane = t & 63;
  const int wid  = t >> 6;        // 0..3
  const int b    = blockIdx.y;

  __shared__ int cs[LENC];        // inclusive cumsum of durations
  __shared__ int wsum[NWAVE];

  // pair-sum scan: thread t owns durations 2t, 2t+1
  const int2 v = dur2[b * (LENC / 2) + t];
  int x = v.x + v.y;
#pragma unroll
  for (int off = 1; off < 64; off <<= 1) {
    const int y = __shfl_up(x, off, 64);
    if (lane >= off) x += y;
  }
  if (lane == 63) wsum[wid] = x;
  __syncthreads();
  int wo = 0;
#pragma unroll
  for (int w = 0; w < NWAVE; ++w) wo += (w < wid) ? wsum[w] : 0;
  const int ip = x + wo;          // inclusive through element 2t+1
  cs[2 * t + 1] = ip;
  cs[2 * t]     = ip - v.y;
  __syncthreads();

  const int total = cs[LENC - 1];
  const int d0 = blockIdx.x * ROWS_PER_BLOCK + wid * ROWS_PER_WAVE;

  // smallest lo with cs[lo] > d0 (wave-uniform, broadcast LDS reads)
  int lo = 0, hi = LENC;
  while (lo < hi) {
    const int mid = (lo + hi) >> 1;
    if (cs[mid] <= d0) lo = mid + 1; else hi = mid;
  }

  // precompute the 4 segment indices (sequential advance, cheap)
  int los[ROWS_PER_WAVE];
#pragma unroll
  for (int r = 0; r < ROWS_PER_WAVE; ++r) {
    while (lo < LENC && cs[lo] <= d0 + r) ++lo;
    los[r] = lo;
  }

  const size_t enc_base = (size_t)b * LENC * E4 + lane;
  const size_t out_base = (size_t)b * LDEC * E4 + (size_t)d0 * E4 + lane;

  // 4 independent loads (MLP), then 4 stores
  float4 vals[ROWS_PER_WAVE];
#pragma unroll
  for (int r = 0; r < ROWS_PER_WAVE; ++r) {
    vals[r] = make_float4(0.f, 0.f, 0.f, 0.f);
    if (d0 + r < total)
      vals[r] = enc[enc_base + (size_t)los[r] * E4];
  }
#pragma unroll
  for (int r = 0; r < ROWS_PER_WAVE; ++r)
    out[out_base + (size_t)r * E4] = vals[r];
}

extern "C" void kernel_launch(void* const* d_in, const int* in_sizes, int n_in,
                              void* d_out, int out_size, void* d_ws, size_t ws_size,
                              hipStream_t stream) {
  const float* enc = (const float*)d_in[0];   // (B, LENC, E) fp32
  const int*   dur = (const int*)d_in[1];     // (B, LENC) int32
  // d_in[2] = decoder_max_seq_len scalar (2048), fixed by harness shapes.

  dim3 grid(LDEC / ROWS_PER_BLOCK, B_);       // (128, 32) = 4096 blocks
  length_regulator_fused<<<grid, TPB, 0, stream>>>(
      (const float4*)enc, (const int2*)dur, (float4*)d_out);
}